// Round 3
// baseline (65.113 us; speedup 1.0000x reference)
//
#include <hip/hip_runtime.h>
#include <hip/hip_bf16.h>

// Problem constants: B=64, T=8192, L=64, NWIN=8128 = 8 * 1016
constexpr int B_SZ  = 64;
constexpr int T_SZ  = 8192;
constexpr int L_SZ  = 64;
constexpr int NWIN  = T_SZ - L_SZ;   // 8128
constexpr int NP    = 8;             // partitions per batch
constexpr int PW    = NWIN / NP;     // 1016 windows per partition (div by 4)
constexpr int STAGE = PW + L_SZ;     // 1080 floats staged per block

// Kernel 1: 512 blocks (B*NP) x 256 threads — 2 blocks/CU, 2 waves/SIMD so the
// second wave hides staging/LDS latency of the first. Each thread evaluates one
// group of 4 consecutive windows (s0 = 4*tid < 1016). Packed argmin key:
// (float_bits(dist)<<32)|global_start — dist>=0 so u64 order == (dist,idx)
// lexicographic, ties -> smallest idx (matches np.argmin first-occurrence).
__global__ __launch_bounds__(256)
void window_match_partial(const float* __restrict__ X_in,
                          const float* __restrict__ X_out,
                          unsigned long long* __restrict__ ws_keys)
{
    __shared__ float xs[STAGE + 8];            // ~4.3 KB
    __shared__ float ys[L_SZ];
    __shared__ unsigned long long wred[4];

    const int bq  = blockIdx.x;
    const int b   = bq >> 3;
    const int p   = bq & 7;
    const int tid = threadIdx.x;
    const int base = p * PW;                   // 1016*p, float4-aligned

    // Stage x[b, base .. base+1079] via float4 (270 vec4 loads over 256 threads)
    const float4* xg  = reinterpret_cast<const float4*>(X_in + (size_t)b * T_SZ + base);
    float4*       xs4 = reinterpret_cast<float4*>(xs);
    for (int i = tid; i < STAGE / 4; i += 256)
        xs4[i] = xg[i];

    if (tid < L_SZ) ys[tid] = X_out[(size_t)b * L_SZ + tid];
    __syncthreads();

    unsigned long long best = ~0ull;

    const int s0 = 4 * tid;                    // local window start, float4-aligned
    if (s0 < PW) {                             // max s0=1012 -> reads xs[..1079]
        float y[L_SZ];
        #pragma unroll
        for (int j = 0; j < L_SZ; ++j) y[j] = ys[j];   // broadcast reads, conflict-free

        // Load x[s0 .. s0+67] as 17 float4 (reused across the 4 windows)
        float xv[68];
        const float4* pp = reinterpret_cast<const float4*>(xs + s0);
        #pragma unroll
        for (int i = 0; i < 17; ++i) {
            float4 v = pp[i];
            xv[4 * i + 0] = v.x;
            xv[4 * i + 1] = v.y;
            xv[4 * i + 2] = v.z;
            xv[4 * i + 3] = v.w;
        }
        #pragma unroll
        for (int w = 0; w < 4; ++w) {
            float d = 0.0f;
            #pragma unroll
            for (int j = 0; j < L_SZ; ++j) {
                const float t = xv[w + j] - y[j];
                d = fmaf(t, t, d);
            }
            const unsigned long long key =
                ((unsigned long long)__float_as_uint(d) << 32) |
                (unsigned int)(base + s0 + w);
            best = key < best ? key : best;
        }
    }

    // Wave (64-lane) shuffle reduce, then cross-wave via LDS
    #pragma unroll
    for (int off = 32; off > 0; off >>= 1) {
        const unsigned long long o = __shfl_down(best, off, 64);
        best = o < best ? o : best;
    }
    if ((tid & 63) == 0) wred[tid >> 6] = best;
    __syncthreads();
    if (tid == 0) {
        unsigned long long m = wred[0];
        m = wred[1] < m ? wred[1] : m;
        m = wred[2] < m ? wred[2] : m;
        m = wred[3] < m ? wred[3] : m;
        ws_keys[bq] = m;
    }
}

// Kernel 2: 64 blocks x 64 threads. Min-reduce the batch's 8 partition keys
// (redundantly in all threads — 8 broadcast loads, no sync) and copy the
// winning 64-float window from global X_in (bit-exact copy of input).
__global__ __launch_bounds__(64)
void window_match_gather(const float* __restrict__ X_in,
                         const unsigned long long* __restrict__ ws_keys,
                         float* __restrict__ out)
{
    const int b   = blockIdx.x;
    const int tid = threadIdx.x;

    unsigned long long m = ws_keys[b * NP + 0];
    #pragma unroll
    for (int q = 1; q < NP; ++q) {
        const unsigned long long o = ws_keys[b * NP + q];
        m = o < m ? o : m;
    }
    const int s = (int)(m & 0xffffffffu);
    out[(size_t)b * L_SZ + tid] = X_in[(size_t)b * T_SZ + s + tid];
}

extern "C" void kernel_launch(void* const* d_in, const int* in_sizes, int n_in,
                              void* d_out, int out_size, void* d_ws, size_t ws_size,
                              hipStream_t stream) {
    // Input order: feats_in (unused), X_in, feats_out (unused), X_out
    const float* X_in  = (const float*)d_in[1];
    const float* X_out = (const float*)d_in[3];
    float* out = (float*)d_out;
    unsigned long long* ws_keys = (unsigned long long*)d_ws;   // 512 * 8 B

    window_match_partial<<<B_SZ * NP, 256, 0, stream>>>(X_in, X_out, ws_keys);
    window_match_gather<<<B_SZ, 64, 0, stream>>>(X_in, ws_keys, out);
}